// Round 1
// baseline (971.111 us; speedup 1.0000x reference)
//
#include <hip/hip_runtime.h>
#include <math.h>

#define NPTS (1u << 20)
#define NLVL 16
#define TBITS 19
#define TSIZE (1u << TBITS)
#define TMASK (TSIZE - 1u)

struct ScaleParams { float s[NLVL]; };

__global__ __launch_bounds__(256)
void hashenc_kernel(const float* __restrict__ x,
                    const float2* __restrict__ table,
                    float2* __restrict__ out,
                    ScaleParams P)
{
    const uint32_t tid = blockIdx.x * 256u + threadIdx.x;
    const uint32_t p = tid >> 4;      // point index
    const uint32_t l = tid & 15u;     // level index

    const float x0 = x[p * 3 + 0];
    const float x1 = x[p * 3 + 1];
    const float x2 = x[p * 3 + 2];
    const float s = P.s[l];

    // scaled coords; single IEEE fp32 multiply matches jnp bit-exactly
    const float sx = x0 * s, sy = x1 * s, sz = x2 * s;
    const float fxf = floorf(sx), fyf = floorf(sy), fzf = floorf(sz);
    const float cxf = ceilf(sx),  cyf = ceilf(sy),  czf = ceilf(sz);
    const float ox = sx - fxf, oy = sy - fyf, oz = sz - fzf;

    const uint32_t fx = (uint32_t)fxf, fy = (uint32_t)fyf, fz = (uint32_t)fzf;
    const uint32_t cx = (uint32_t)cxf, cy = (uint32_t)cyf, cz = (uint32_t)czf;

    const uint32_t PR1 = 2654435761u, PR2 = 805459861u;
    const uint32_t Xf = fx,        Xc = cx;         // prime 1
    const uint32_t Yf = fy * PR1,  Yc = cy * PR1;
    const uint32_t Zf = fz * PR2,  Zc = cz * PR2;

    const uint32_t base = l << TBITS;
    // corner order per CORNER_MASK rows 0..7
    const uint32_t i0 = ((Xc ^ Yc ^ Zc) & TMASK) + base;  // [1,1,1]
    const uint32_t i1 = ((Xc ^ Yf ^ Zc) & TMASK) + base;  // [1,0,1]
    const uint32_t i2 = ((Xf ^ Yf ^ Zc) & TMASK) + base;  // [0,0,1]
    const uint32_t i3 = ((Xf ^ Yc ^ Zc) & TMASK) + base;  // [0,1,1]
    const uint32_t i4 = ((Xc ^ Yc ^ Zf) & TMASK) + base;  // [1,1,0]
    const uint32_t i5 = ((Xc ^ Yf ^ Zf) & TMASK) + base;  // [1,0,0]
    const uint32_t i6 = ((Xf ^ Yf ^ Zf) & TMASK) + base;  // [0,0,0]
    const uint32_t i7 = ((Xf ^ Yc ^ Zf) & TMASK) + base;  // [0,1,0]

    const float2 f0 = table[i0], f1 = table[i1], f2 = table[i2], f3 = table[i3];
    const float2 f4 = table[i4], f5 = table[i5], f6 = table[i6], f7 = table[i7];

    const float omx = 1.0f - ox, omy = 1.0f - oy, omz = 1.0f - oz;
    // x-lerps: f03, f12, f56, f47
    const float a0 = f0.x * ox + f3.x * omx, b0 = f0.y * ox + f3.y * omx;
    const float a1 = f1.x * ox + f2.x * omx, b1 = f1.y * ox + f2.y * omx;
    const float a2 = f5.x * ox + f6.x * omx, b2 = f5.y * ox + f6.y * omx;
    const float a3 = f4.x * ox + f7.x * omx, b3 = f4.y * ox + f7.y * omx;
    // y-lerps: f0312 = f03*oy + f12*(1-oy); f4756 = f47*oy + f56*(1-oy)
    const float c0 = a0 * oy + a1 * omy, d0 = b0 * oy + b1 * omy;
    const float c1 = a3 * oy + a2 * omy, d1 = b3 * oy + b2 * omy;
    // z-lerp
    const float ex = c0 * oz + c1 * omz, ey = d0 * oz + d1 * omz;

    out[p * 16u + l] = make_float2(ex, ey);
}

extern "C" void kernel_launch(void* const* d_in, const int* in_sizes, int n_in,
                              void* d_out, int out_size, void* d_ws, size_t ws_size,
                              hipStream_t stream) {
    const float*  x     = (const float*)d_in[0];
    const float2* table = (const float2*)d_in[1];
    float2*       out   = (float2*)d_out;

    // Replicate numpy's float64 computation of SCALINGS with glibc libm,
    // identical operation order: growth = exp((log(4096)-log(16))/15);
    // scale_l = floor(16 * growth**l). Level 15 is the 4095-vs-4096
    // boundary case — host double math mirrors the reference pipeline.
    ScaleParams P;
    const double growth = exp((log(4096.0) - log(16.0)) / 15.0);
    for (int l = 0; l < NLVL; ++l) {
        P.s[l] = (float)floor(16.0 * pow(growth, (double)l));
    }

    const uint32_t total = NPTS * NLVL;          // 16,777,216 threads
    dim3 grid(total / 256u), block(256u);
    hipLaunchKernelGGL(hashenc_kernel, grid, block, 0, stream,
                       x, table, out, P);
}

// Round 2
// 611.795 us; speedup vs baseline: 1.5873x; 1.5873x over previous
//
#include <hip/hip_runtime.h>
#include <math.h>

#define NPTS   (1u << 20)
#define NLVL   16
#define TBITS  19
#define TMASK  ((1u << TBITS) - 1u)
#define PTS_PER_BLK 256u
#define CHUNKS (NPTS / PTS_PER_BLK)   // 4096 blocks per level

struct ScaleParams { float s[NLVL]; };

// ---------------------------------------------------------------------------
// Kernel 1: level-major gather. blockIdx = level*CHUNKS + chunk, so the chip
// sweeps one level at a time; each level's 4 MiB table segment fits exactly
// in one XCD L2 (replicated across XCDs). Writes level-major to ws (coalesced).
// ---------------------------------------------------------------------------
__global__ __launch_bounds__(256)
void gather_kernel(const float* __restrict__ x,
                   const float2* __restrict__ table,
                   float2* __restrict__ ws,
                   ScaleParams P)
{
    const uint32_t l = blockIdx.x / CHUNKS;       // level (phase-ordered)
    const uint32_t c = blockIdx.x % CHUNKS;       // chunk within level
    const uint32_t p = c * PTS_PER_BLK + threadIdx.x;

    const float x0 = x[p * 3 + 0];
    const float x1 = x[p * 3 + 1];
    const float x2 = x[p * 3 + 2];
    const float s  = P.s[l];

    const float sx = x0 * s, sy = x1 * s, sz = x2 * s;
    const float fxf = floorf(sx), fyf = floorf(sy), fzf = floorf(sz);
    const float cxf = ceilf(sx),  cyf = ceilf(sy),  czf = ceilf(sz);
    const float ox = sx - fxf, oy = sy - fyf, oz = sz - fzf;

    const uint32_t PR1 = 2654435761u, PR2 = 805459861u;
    const uint32_t Xf = (uint32_t)fxf,        Xc = (uint32_t)cxf;
    const uint32_t Yf = (uint32_t)fyf * PR1,  Yc = (uint32_t)cyf * PR1;
    const uint32_t Zf = (uint32_t)fzf * PR2,  Zc = (uint32_t)czf * PR2;

    const uint32_t base = l << TBITS;
    const uint32_t i0 = ((Xc ^ Yc ^ Zc) & TMASK) + base;  // [1,1,1]
    const uint32_t i1 = ((Xc ^ Yf ^ Zc) & TMASK) + base;  // [1,0,1]
    const uint32_t i2 = ((Xf ^ Yf ^ Zc) & TMASK) + base;  // [0,0,1]
    const uint32_t i3 = ((Xf ^ Yc ^ Zc) & TMASK) + base;  // [0,1,1]
    const uint32_t i4 = ((Xc ^ Yc ^ Zf) & TMASK) + base;  // [1,1,0]
    const uint32_t i5 = ((Xc ^ Yf ^ Zf) & TMASK) + base;  // [1,0,0]
    const uint32_t i6 = ((Xf ^ Yf ^ Zf) & TMASK) + base;  // [0,0,0]
    const uint32_t i7 = ((Xf ^ Yc ^ Zf) & TMASK) + base;  // [0,1,0]

    const float2 f0 = table[i0], f1 = table[i1], f2 = table[i2], f3 = table[i3];
    const float2 f4 = table[i4], f5 = table[i5], f6 = table[i6], f7 = table[i7];

    const float omx = 1.0f - ox, omy = 1.0f - oy, omz = 1.0f - oz;
    const float a0 = f0.x * ox + f3.x * omx, b0 = f0.y * ox + f3.y * omx;
    const float a1 = f1.x * ox + f2.x * omx, b1 = f1.y * ox + f2.y * omx;
    const float a2 = f5.x * ox + f6.x * omx, b2 = f5.y * ox + f6.y * omx;
    const float a3 = f4.x * ox + f7.x * omx, b3 = f4.y * ox + f7.y * omx;
    const float c0 = a0 * oy + a1 * omy, d0 = b0 * oy + b1 * omy;
    const float c1 = a3 * oy + a2 * omy, d1 = b3 * oy + b2 * omy;
    const float ex = c0 * oz + c1 * omz, ey = d0 * oz + d1 * omz;

    ws[l * NPTS + p] = make_float2(ex, ey);   // level-major, coalesced
}

// ---------------------------------------------------------------------------
// Kernel 2: transpose ws[l][p] -> out[p][l]. Reads coalesced per level;
// each thread writes its point's 128 contiguous bytes as 8 float4s.
// ---------------------------------------------------------------------------
__global__ __launch_bounds__(256)
void transpose_kernel(const float2* __restrict__ ws, float4* __restrict__ out4)
{
    const uint32_t p = blockIdx.x * 256u + threadIdx.x;
    float2 v[NLVL];
    #pragma unroll
    for (int l = 0; l < NLVL; ++l) v[l] = ws[(uint32_t)l * NPTS + p];
    #pragma unroll
    for (int j = 0; j < 8; ++j)
        out4[p * 8u + j] = make_float4(v[2*j].x, v[2*j].y, v[2*j+1].x, v[2*j+1].y);
}

// ---------------------------------------------------------------------------
// Fallback (round-1 kernel) if ws is too small for the level-major staging.
// ---------------------------------------------------------------------------
__global__ __launch_bounds__(256)
void hashenc_fused(const float* __restrict__ x,
                   const float2* __restrict__ table,
                   float2* __restrict__ out,
                   ScaleParams P)
{
    const uint32_t tid = blockIdx.x * 256u + threadIdx.x;
    const uint32_t p = tid >> 4;
    const uint32_t l = tid & 15u;

    const float x0 = x[p * 3 + 0];
    const float x1 = x[p * 3 + 1];
    const float x2 = x[p * 3 + 2];
    const float s  = P.s[l];

    const float sx = x0 * s, sy = x1 * s, sz = x2 * s;
    const float fxf = floorf(sx), fyf = floorf(sy), fzf = floorf(sz);
    const float cxf = ceilf(sx),  cyf = ceilf(sy),  czf = ceilf(sz);
    const float ox = sx - fxf, oy = sy - fyf, oz = sz - fzf;

    const uint32_t PR1 = 2654435761u, PR2 = 805459861u;
    const uint32_t Xf = (uint32_t)fxf,        Xc = (uint32_t)cxf;
    const uint32_t Yf = (uint32_t)fyf * PR1,  Yc = (uint32_t)cyf * PR1;
    const uint32_t Zf = (uint32_t)fzf * PR2,  Zc = (uint32_t)czf * PR2;

    const uint32_t base = l << TBITS;
    const uint32_t i0 = ((Xc ^ Yc ^ Zc) & TMASK) + base;
    const uint32_t i1 = ((Xc ^ Yf ^ Zc) & TMASK) + base;
    const uint32_t i2 = ((Xf ^ Yf ^ Zc) & TMASK) + base;
    const uint32_t i3 = ((Xf ^ Yc ^ Zc) & TMASK) + base;
    const uint32_t i4 = ((Xc ^ Yc ^ Zf) & TMASK) + base;
    const uint32_t i5 = ((Xc ^ Yf ^ Zf) & TMASK) + base;
    const uint32_t i6 = ((Xf ^ Yf ^ Zf) & TMASK) + base;
    const uint32_t i7 = ((Xf ^ Yc ^ Zf) & TMASK) + base;

    const float2 f0 = table[i0], f1 = table[i1], f2 = table[i2], f3 = table[i3];
    const float2 f4 = table[i4], f5 = table[i5], f6 = table[i6], f7 = table[i7];

    const float omx = 1.0f - ox, omy = 1.0f - oy, omz = 1.0f - oz;
    const float a0 = f0.x * ox + f3.x * omx, b0 = f0.y * ox + f3.y * omx;
    const float a1 = f1.x * ox + f2.x * omx, b1 = f1.y * ox + f2.y * omx;
    const float a2 = f5.x * ox + f6.x * omx, b2 = f5.y * ox + f6.y * omx;
    const float a3 = f4.x * ox + f7.x * omx, b3 = f4.y * ox + f7.y * omx;
    const float c0 = a0 * oy + a1 * omy, d0 = b0 * oy + b1 * omy;
    const float c1 = a3 * oy + a2 * omy, d1 = b3 * oy + b2 * omy;
    const float ex = c0 * oz + c1 * omz, ey = d0 * oz + d1 * omz;

    out[p * 16u + l] = make_float2(ex, ey);
}

extern "C" void kernel_launch(void* const* d_in, const int* in_sizes, int n_in,
                              void* d_out, int out_size, void* d_ws, size_t ws_size,
                              hipStream_t stream) {
    const float*  x     = (const float*)d_in[0];
    const float2* table = (const float2*)d_in[1];

    // SCALINGS: replicate numpy float64 pipeline in identical op order.
    ScaleParams P;
    const double growth = exp((log(4096.0) - log(16.0)) / 15.0);
    for (int l = 0; l < NLVL; ++l)
        P.s[l] = (float)floor(16.0 * pow(growth, (double)l));

    const size_t ws_needed = (size_t)NPTS * NLVL * sizeof(float2);  // 128 MiB

    if (ws_size >= ws_needed) {
        float2* ws   = (float2*)d_ws;
        float4* out4 = (float4*)d_out;
        dim3 grid1(NLVL * CHUNKS), block(256u);
        hipLaunchKernelGGL(gather_kernel, grid1, block, 0, stream, x, table, ws, P);
        dim3 grid2(NPTS / 256u);
        hipLaunchKernelGGL(transpose_kernel, grid2, block, 0, stream, ws, out4);
    } else {
        float2* out = (float2*)d_out;
        dim3 grid(NPTS * NLVL / 256u), block(256u);
        hipLaunchKernelGGL(hashenc_fused, grid, block, 0, stream, x, table, out, P);
    }
}

// Round 3
// 400.176 us; speedup vs baseline: 2.4267x; 1.5288x over previous
//
#include <hip/hip_runtime.h>
#include <math.h>

#define NPTS   (1u << 20)
#define NLVL   16
#define TBITS  19
#define TMASK  ((1u << TBITS) - 1u)
#define PTS_PER_BLK 256u
#define CHUNKS (NPTS / PTS_PER_BLK)   // 4096 blocks per level

struct ScaleParams { float s[NLVL]; };

// Load an adjacent-pair of table entries (iF and iC = iF^1) with one float4.
__device__ __forceinline__ void pairload(const float4* __restrict__ t4,
                                         uint32_t iF, float2& vF, float2& vC) {
    const float4 q = t4[iF >> 1];          // entries {iF&~1, iF|1}
    if (iF & 1u) { vF = make_float2(q.z, q.w); vC = make_float2(q.x, q.y); }
    else         { vF = make_float2(q.x, q.y); vC = make_float2(q.z, q.w); }
}

// ---------------------------------------------------------------------------
// Kernel 1: level-major gather (level-phased for L2 residency) + corner
// pair-merge. Writes level-major to ws (coalesced).
// ---------------------------------------------------------------------------
__global__ __launch_bounds__(256)
void gather_kernel(const float* __restrict__ x,
                   const float2* __restrict__ table,
                   float2* __restrict__ ws,
                   ScaleParams P)
{
    const uint32_t l = blockIdx.x / CHUNKS;
    const uint32_t c = blockIdx.x % CHUNKS;
    const uint32_t p = c * PTS_PER_BLK + threadIdx.x;

    const float x0 = x[p * 3 + 0];
    const float x1 = x[p * 3 + 1];
    const float x2 = x[p * 3 + 2];
    const float s  = P.s[l];

    const float sx = x0 * s, sy = x1 * s, sz = x2 * s;
    const float fxf = floorf(sx), fyf = floorf(sy), fzf = floorf(sz);
    const float cxf = ceilf(sx),  cyf = ceilf(sy),  czf = ceilf(sz);
    const float ox = sx - fxf, oy = sy - fyf, oz = sz - fzf;

    const uint32_t PR1 = 2654435761u, PR2 = 805459861u;
    const uint32_t fx = (uint32_t)fxf, cx = (uint32_t)cxf;
    const uint32_t Yf = (uint32_t)fyf * PR1,  Yc = (uint32_t)cyf * PR1;
    const uint32_t Zf = (uint32_t)fzf * PR2,  Zc = (uint32_t)czf * PR2;

    const uint32_t base = l << TBITS;
    // f/c differ only in x; x-prime == 1, so iC = iF ^ (fx^cx) for every pair.
    const uint32_t i0 = ((cx ^ Yc ^ Zc) & TMASK) + base;  // [1,1,1]
    const uint32_t i1 = ((cx ^ Yf ^ Zc) & TMASK) + base;  // [1,0,1]
    const uint32_t i2 = ((fx ^ Yf ^ Zc) & TMASK) + base;  // [0,0,1]
    const uint32_t i3 = ((fx ^ Yc ^ Zc) & TMASK) + base;  // [0,1,1]
    const uint32_t i4 = ((cx ^ Yc ^ Zf) & TMASK) + base;  // [1,1,0]
    const uint32_t i5 = ((cx ^ Yf ^ Zf) & TMASK) + base;  // [1,0,0]
    const uint32_t i6 = ((fx ^ Yf ^ Zf) & TMASK) + base;  // [0,0,0]
    const uint32_t i7 = ((fx ^ Yc ^ Zf) & TMASK) + base;  // [0,1,0]

    float2 f0, f1, f2, f3, f4, f5, f6, f7;
    if ((fx ^ cx) == 1u) {
        // all four {f,c} pairs are aligned adjacent entries: 4 float4 loads
        const float4* t4 = (const float4*)table;
        pairload(t4, i3, f3, f0);   // pair {i3 (f), i0 (c)}
        pairload(t4, i2, f2, f1);   // pair {i2 (f), i1 (c)}
        pairload(t4, i7, f7, f4);   // pair {i7 (f), i4 (c)}
        pairload(t4, i6, f6, f5);   // pair {i6 (f), i5 (c)}
    } else {
        f0 = table[i0]; f1 = table[i1]; f2 = table[i2]; f3 = table[i3];
        f4 = table[i4]; f5 = table[i5]; f6 = table[i6]; f7 = table[i7];
    }

    const float omx = 1.0f - ox, omy = 1.0f - oy, omz = 1.0f - oz;
    const float a0 = f0.x * ox + f3.x * omx, b0 = f0.y * ox + f3.y * omx;
    const float a1 = f1.x * ox + f2.x * omx, b1 = f1.y * ox + f2.y * omx;
    const float a2 = f5.x * ox + f6.x * omx, b2 = f5.y * ox + f6.y * omx;
    const float a3 = f4.x * ox + f7.x * omx, b3 = f4.y * ox + f7.y * omx;
    const float c0 = a0 * oy + a1 * omy, d0 = b0 * oy + b1 * omy;
    const float c1 = a3 * oy + a2 * omy, d1 = b3 * oy + b2 * omy;
    const float ex = c0 * oz + c1 * omz, ey = d0 * oz + d1 * omz;

    ws[l * NPTS + p] = make_float2(ex, ey);
}

// ---------------------------------------------------------------------------
// Kernel 2: transpose ws[l][p] -> out[p][l]. Element e = p*8 + lp (lp = level
// pair). Within a wave, lanes cover 8 fully-covered 64B lines on BOTH the
// read and the write side.
// ---------------------------------------------------------------------------
__global__ __launch_bounds__(256)
void transpose_kernel(const float2* __restrict__ ws, float4* __restrict__ out4)
{
    const uint32_t e  = blockIdx.x * 256u + threadIdx.x;  // float4 index
    const uint32_t p  = e >> 3;
    const uint32_t lp = e & 7u;
    const float2 a = ws[(2u * lp)     * NPTS + p];
    const float2 b = ws[(2u * lp + 1) * NPTS + p];
    out4[e] = make_float4(a.x, a.y, b.x, b.y);
}

// ---------------------------------------------------------------------------
// Fallback (round-1 fused kernel) if ws is too small.
// ---------------------------------------------------------------------------
__global__ __launch_bounds__(256)
void hashenc_fused(const float* __restrict__ x,
                   const float2* __restrict__ table,
                   float2* __restrict__ out,
                   ScaleParams P)
{
    const uint32_t tid = blockIdx.x * 256u + threadIdx.x;
    const uint32_t p = tid >> 4;
    const uint32_t l = tid & 15u;

    const float x0 = x[p * 3 + 0];
    const float x1 = x[p * 3 + 1];
    const float x2 = x[p * 3 + 2];
    const float s  = P.s[l];

    const float sx = x0 * s, sy = x1 * s, sz = x2 * s;
    const float fxf = floorf(sx), fyf = floorf(sy), fzf = floorf(sz);
    const float cxf = ceilf(sx),  cyf = ceilf(sy),  czf = ceilf(sz);
    const float ox = sx - fxf, oy = sy - fyf, oz = sz - fzf;

    const uint32_t PR1 = 2654435761u, PR2 = 805459861u;
    const uint32_t Xf = (uint32_t)fxf,        Xc = (uint32_t)cxf;
    const uint32_t Yf = (uint32_t)fyf * PR1,  Yc = (uint32_t)cyf * PR1;
    const uint32_t Zf = (uint32_t)fzf * PR2,  Zc = (uint32_t)czf * PR2;

    const uint32_t base = l << TBITS;
    const uint32_t i0 = ((Xc ^ Yc ^ Zc) & TMASK) + base;
    const uint32_t i1 = ((Xc ^ Yf ^ Zc) & TMASK) + base;
    const uint32_t i2 = ((Xf ^ Yf ^ Zc) & TMASK) + base;
    const uint32_t i3 = ((Xf ^ Yc ^ Zc) & TMASK) + base;
    const uint32_t i4 = ((Xc ^ Yc ^ Zf) & TMASK) + base;
    const uint32_t i5 = ((Xc ^ Yf ^ Zf) & TMASK) + base;
    const uint32_t i6 = ((Xf ^ Yf ^ Zf) & TMASK) + base;
    const uint32_t i7 = ((Xf ^ Yc ^ Zf) & TMASK) + base;

    const float2 f0 = table[i0], f1 = table[i1], f2 = table[i2], f3 = table[i3];
    const float2 f4 = table[i4], f5 = table[i5], f6 = table[i6], f7 = table[i7];

    const float omx = 1.0f - ox, omy = 1.0f - oy, omz = 1.0f - oz;
    const float a0 = f0.x * ox + f3.x * omx, b0 = f0.y * ox + f3.y * omx;
    const float a1 = f1.x * ox + f2.x * omx, b1 = f1.y * ox + f2.y * omx;
    const float a2 = f5.x * ox + f6.x * omx, b2 = f5.y * ox + f6.y * omx;
    const float a3 = f4.x * ox + f7.x * omx, b3 = f4.y * ox + f7.y * omx;
    const float c0 = a0 * oy + a1 * omy, d0 = b0 * oy + b1 * omy;
    const float c1 = a3 * oy + a2 * omy, d1 = b3 * oy + b2 * omy;
    const float ex = c0 * oz + c1 * omz, ey = d0 * oz + d1 * omz;

    out[p * 16u + l] = make_float2(ex, ey);
}

extern "C" void kernel_launch(void* const* d_in, const int* in_sizes, int n_in,
                              void* d_out, int out_size, void* d_ws, size_t ws_size,
                              hipStream_t stream) {
    const float*  x     = (const float*)d_in[0];
    const float2* table = (const float2*)d_in[1];

    // SCALINGS: replicate numpy float64 pipeline in identical op order.
    ScaleParams P;
    const double growth = exp((log(4096.0) - log(16.0)) / 15.0);
    for (int l = 0; l < NLVL; ++l)
        P.s[l] = (float)floor(16.0 * pow(growth, (double)l));

    const size_t ws_needed = (size_t)NPTS * NLVL * sizeof(float2);  // 128 MiB

    if (ws_size >= ws_needed) {
        float2* ws   = (float2*)d_ws;
        float4* out4 = (float4*)d_out;
        dim3 block(256u);
        dim3 grid1(NLVL * CHUNKS);
        hipLaunchKernelGGL(gather_kernel, grid1, block, 0, stream, x, table, ws, P);
        dim3 grid2(NPTS * 8u / 256u);   // one float4 element per thread
        hipLaunchKernelGGL(transpose_kernel, grid2, block, 0, stream, ws, out4);
    } else {
        float2* out = (float2*)d_out;
        dim3 grid(NPTS * NLVL / 256u), block(256u);
        hipLaunchKernelGGL(hashenc_fused, grid, block, 0, stream, x, table, out, P);
    }
}

// Round 4
// 399.063 us; speedup vs baseline: 2.4335x; 1.0028x over previous
//
#include <hip/hip_runtime.h>
#include <math.h>

#define NPTS   (1u << 20)
#define NLVL   16
#define TBITS  19
#define TMASK  ((1u << TBITS) - 1u)
#define CHUNKS2 (NPTS / 128u)          // 8192 blocks/level, 128 points per block

struct ScaleParams { float s[NLVL]; };

// ---------------------------------------------------------------------------
// Kernel 1: level-phased gather, TWO lanes per (point,level).
// Lane0 = floor-x corners, lane1 = ceil-x corners. Even-parity pairs load one
// shared float4 (1 request); odd-parity pairs issue lane-paired float2 loads
// that TA-coalesce to 1 request when same 64B line (3/4 of odd cases).
// ---------------------------------------------------------------------------
__global__ __launch_bounds__(256)
void gather2_kernel(const float* __restrict__ x,
                    const float2* __restrict__ table,
                    float2* __restrict__ ws,
                    ScaleParams P)
{
    const uint32_t lane_c = threadIdx.x & 1u;      // 0=floor side, 1=ceil side
    const uint32_t unit   = threadIdx.x >> 1;      // 0..127
    const uint32_t l = blockIdx.x / CHUNKS2;
    const uint32_t c = blockIdx.x % CHUNKS2;
    const uint32_t p = c * 128u + unit;

    const float x0 = x[p * 3 + 0];
    const float x1 = x[p * 3 + 1];
    const float x2 = x[p * 3 + 2];
    const float s  = P.s[l];

    const float sx = x0 * s, sy = x1 * s, sz = x2 * s;
    const float fxf = floorf(sx), fyf = floorf(sy), fzf = floorf(sz);
    const float cxf = ceilf(sx),  cyf = ceilf(sy),  czf = ceilf(sz);
    const float ox = sx - fxf, oy = sy - fyf, oz = sz - fzf;

    const uint32_t PR1 = 2654435761u, PR2 = 805459861u;
    const uint32_t fx = (uint32_t)fxf, cx = (uint32_t)cxf;
    const uint32_t Yf = (uint32_t)fyf * PR1,  Yc = (uint32_t)cyf * PR1;
    const uint32_t Zf = (uint32_t)fzf * PR2,  Zc = (uint32_t)czf * PR2;
    const uint32_t base = l << TBITS;

    // Pair A: (Yc,Zc) -> f03 ; B: (Yf,Zc) -> f12 ; C: (Yc,Zf) -> f47 ; D: (Yf,Zf) -> f56
    const uint32_t iA_f = ((fx ^ Yc ^ Zc) & TMASK) + base;
    const uint32_t iA_c = ((cx ^ Yc ^ Zc) & TMASK) + base;
    const uint32_t iB_f = ((fx ^ Yf ^ Zc) & TMASK) + base;
    const uint32_t iB_c = ((cx ^ Yf ^ Zc) & TMASK) + base;
    const uint32_t iC_f = ((fx ^ Yc ^ Zf) & TMASK) + base;
    const uint32_t iC_c = ((cx ^ Yc ^ Zf) & TMASK) + base;
    const uint32_t iD_f = ((fx ^ Yf ^ Zf) & TMASK) + base;
    const uint32_t iD_c = ((cx ^ Yf ^ Zf) & TMASK) + base;

    float2 vA, vB, vC, vD;   // this lane's corner of each pair
    if ((fx ^ cx) == 1u) {
        // aligned adjacent pairs: both lanes load the SAME float4 (1 request),
        // then select halves: entry iF lives in half (iF&1); lane_c takes other.
        const float4* t4 = (const float4*)table;
        const float4 qA = t4[iA_f >> 1];
        const float4 qB = t4[iB_f >> 1];
        const float4 qC = t4[iC_f >> 1];
        const float4 qD = t4[iD_f >> 1];
        const uint32_t hA = (iA_f & 1u) ^ lane_c;
        const uint32_t hB = (iB_f & 1u) ^ lane_c;
        const uint32_t hC = (iC_f & 1u) ^ lane_c;
        const uint32_t hD = (iD_f & 1u) ^ lane_c;
        vA = hA ? make_float2(qA.z, qA.w) : make_float2(qA.x, qA.y);
        vB = hB ? make_float2(qB.z, qB.w) : make_float2(qB.x, qB.y);
        vC = hC ? make_float2(qC.z, qC.w) : make_float2(qC.x, qC.y);
        vD = hD ? make_float2(qD.z, qD.w) : make_float2(qD.x, qD.y);
    } else {
        // lane-paired gathers: lane0->iF, lane1->iC in the same instruction;
        // same-line pairs (m=3,7) coalesce to one L2 request.
        vA = table[lane_c ? iA_c : iA_f];
        vB = table[lane_c ? iB_c : iB_f];
        vC = table[lane_c ? iC_c : iC_f];
        vD = table[lane_c ? iD_c : iD_f];
    }

    // x-lerp across the lane pair: c-side weight = ox, f-side = 1-ox
    const float wx = lane_c ? ox : (1.0f - ox);
    float pAx = vA.x * wx, pAy = vA.y * wx;
    float pBx = vB.x * wx, pBy = vB.y * wx;
    float pCx = vC.x * wx, pCy = vC.y * wx;
    float pDx = vD.x * wx, pDy = vD.y * wx;

    const float fAx = pAx + __shfl_xor(pAx, 1);   // f03
    const float fAy = pAy + __shfl_xor(pAy, 1);
    const float fBx = pBx + __shfl_xor(pBx, 1);   // f12
    const float fBy = pBy + __shfl_xor(pBy, 1);
    const float fCx = pCx + __shfl_xor(pCx, 1);   // f47
    const float fCy = pCy + __shfl_xor(pCy, 1);
    const float fDx = pDx + __shfl_xor(pDx, 1);   // f56
    const float fDy = pDy + __shfl_xor(pDy, 1);

    const float omy = 1.0f - oy, omz = 1.0f - oz;
    const float ex = (fAx * oy + fBx * omy) * oz + (fCx * oy + fDx * omy) * omz;
    const float ey = (fAy * oy + fBy * omy) * oz + (fCy * oy + fDy * omy) * omz;

    if (lane_c == 0u)
        ws[l * NPTS + p] = make_float2(ex, ey);
}

// ---------------------------------------------------------------------------
// Kernel 2: transpose ws[l][p] -> out[p][l], line-coalesced both sides.
// ---------------------------------------------------------------------------
__global__ __launch_bounds__(256)
void transpose_kernel(const float2* __restrict__ ws, float4* __restrict__ out4)
{
    const uint32_t e  = blockIdx.x * 256u + threadIdx.x;
    const uint32_t p  = e >> 3;
    const uint32_t lp = e & 7u;
    const float2 a = ws[(2u * lp)     * NPTS + p];
    const float2 b = ws[(2u * lp + 1) * NPTS + p];
    out4[e] = make_float4(a.x, a.y, b.x, b.y);
}

// ---------------------------------------------------------------------------
// Fallback (fused) if ws is too small.
// ---------------------------------------------------------------------------
__global__ __launch_bounds__(256)
void hashenc_fused(const float* __restrict__ x,
                   const float2* __restrict__ table,
                   float2* __restrict__ out,
                   ScaleParams P)
{
    const uint32_t tid = blockIdx.x * 256u + threadIdx.x;
    const uint32_t p = tid >> 4;
    const uint32_t l = tid & 15u;

    const float x0 = x[p * 3 + 0];
    const float x1 = x[p * 3 + 1];
    const float x2 = x[p * 3 + 2];
    const float s  = P.s[l];

    const float sx = x0 * s, sy = x1 * s, sz = x2 * s;
    const float fxf = floorf(sx), fyf = floorf(sy), fzf = floorf(sz);
    const float cxf = ceilf(sx),  cyf = ceilf(sy),  czf = ceilf(sz);
    const float ox = sx - fxf, oy = sy - fyf, oz = sz - fzf;

    const uint32_t PR1 = 2654435761u, PR2 = 805459861u;
    const uint32_t Xf = (uint32_t)fxf,        Xc = (uint32_t)cxf;
    const uint32_t Yf = (uint32_t)fyf * PR1,  Yc = (uint32_t)cyf * PR1;
    const uint32_t Zf = (uint32_t)fzf * PR2,  Zc = (uint32_t)czf * PR2;

    const uint32_t base = l << TBITS;
    const uint32_t i0 = ((Xc ^ Yc ^ Zc) & TMASK) + base;
    const uint32_t i1 = ((Xc ^ Yf ^ Zc) & TMASK) + base;
    const uint32_t i2 = ((Xf ^ Yf ^ Zc) & TMASK) + base;
    const uint32_t i3 = ((Xf ^ Yc ^ Zc) & TMASK) + base;
    const uint32_t i4 = ((Xc ^ Yc ^ Zf) & TMASK) + base;
    const uint32_t i5 = ((Xc ^ Yf ^ Zf) & TMASK) + base;
    const uint32_t i6 = ((Xf ^ Yf ^ Zf) & TMASK) + base;
    const uint32_t i7 = ((Xf ^ Yc ^ Zf) & TMASK) + base;

    const float2 f0 = table[i0], f1 = table[i1], f2 = table[i2], f3 = table[i3];
    const float2 f4 = table[i4], f5 = table[i5], f6 = table[i6], f7 = table[i7];

    const float omx = 1.0f - ox, omy = 1.0f - oy, omz = 1.0f - oz;
    const float a0 = f0.x * ox + f3.x * omx, b0 = f0.y * ox + f3.y * omx;
    const float a1 = f1.x * ox + f2.x * omx, b1 = f1.y * ox + f2.y * omx;
    const float a2 = f5.x * ox + f6.x * omx, b2 = f5.y * ox + f6.y * omx;
    const float a3 = f4.x * ox + f7.x * omx, b3 = f4.y * ox + f7.y * omx;
    const float c0 = a0 * oy + a1 * omy, d0 = b0 * oy + b1 * omy;
    const float c1 = a3 * oy + a2 * omy, d1 = b3 * oy + b2 * omy;
    const float ex = c0 * oz + c1 * omz, ey = d0 * oz + d1 * omz;

    out[p * 16u + l] = make_float2(ex, ey);
}

extern "C" void kernel_launch(void* const* d_in, const int* in_sizes, int n_in,
                              void* d_out, int out_size, void* d_ws, size_t ws_size,
                              hipStream_t stream) {
    const float*  x     = (const float*)d_in[0];
    const float2* table = (const float2*)d_in[1];

    // SCALINGS: replicate numpy float64 pipeline in identical op order.
    ScaleParams P;
    const double growth = exp((log(4096.0) - log(16.0)) / 15.0);
    for (int l = 0; l < NLVL; ++l)
        P.s[l] = (float)floor(16.0 * pow(growth, (double)l));

    const size_t ws_needed = (size_t)NPTS * NLVL * sizeof(float2);  // 128 MiB

    if (ws_size >= ws_needed) {
        float2* ws   = (float2*)d_ws;
        float4* out4 = (float4*)d_out;
        dim3 block(256u);
        dim3 grid1(NLVL * CHUNKS2);            // 2 lanes per (point,level)
        hipLaunchKernelGGL(gather2_kernel, grid1, block, 0, stream, x, table, ws, P);
        dim3 grid2(NPTS * 8u / 256u);
        hipLaunchKernelGGL(transpose_kernel, grid2, block, 0, stream, ws, out4);
    } else {
        float2* out = (float2*)d_out;
        dim3 grid(NPTS * NLVL / 256u), block(256u);
        hipLaunchKernelGGL(hashenc_fused, grid, block, 0, stream, x, table, out, P);
    }
}